// Round 2
// baseline (174.167 us; speedup 1.0000x reference)
//
#include <hip/hip_runtime.h>

#define B_ROWS 2048
#define S_LEN 8192
#define SEG_OUT 1024
#define WARM 256
#define EXT (SEG_OUT + WARM)            // 1280 = 64 * 20
#define PER_LANE (EXT / 64)             // 20 floats/lane = 5 float4
#define NSEG (S_LEN / SEG_OUT)          // 8 segments per row
#define WPB 4                           // waves per block
#define NBLOCKS (B_ROWS * NSEG / WPB)   // 4096 blocks

// ---- compile-time decay constants, trimmed below 1e-12 (error << 9e-3 tol) ----
constexpr double cpowi(double b, int e) { double r = 1.0; for (int i = 0; i < e; ++i) r *= b; return r; }
constexpr float trim(double x) { return (x < 1e-12 && x > -1e-12) ? 0.0f : (float)x; }

#define A0f 0.1f
#define A1f 0.3f
#define A2f 0.6f

// d_k = (1-alpha)^(PER_LANE * 2^k)
constexpr float D0_1 = trim(cpowi(0.9, 20)),  D0_2 = trim(cpowi(0.9, 40)),  D0_4 = trim(cpowi(0.9, 80));
constexpr float D0_8 = trim(cpowi(0.9, 160)), D0_16 = trim(cpowi(0.9, 320)), D0_32 = trim(cpowi(0.9, 640));
constexpr float D1_1 = trim(cpowi(0.7, 20)),  D1_2 = trim(cpowi(0.7, 40)),  D1_4 = trim(cpowi(0.7, 80));
constexpr float D1_8 = trim(cpowi(0.7, 160)), D1_16 = trim(cpowi(0.7, 320)), D1_32 = trim(cpowi(0.7, 640));
constexpr float D2_1 = trim(cpowi(0.4, 20)),  D2_2 = trim(cpowi(0.4, 40)),  D2_4 = trim(cpowi(0.4, 80));
constexpr float D2_8 = trim(cpowi(0.4, 160)), D2_16 = trim(cpowi(0.4, 320)), D2_32 = trim(cpowi(0.4, 640));

// Kogge-Stone scan for the linear recurrence; compile-time-zero steps are elided.
__device__ __forceinline__ float ema_scan(float v, int lane,
                                          float d1, float d2, float d4,
                                          float d8, float d16, float d32) {
    float u;
    if (d1 != 0.0f) { u = __shfl_up(v, 1);  v += (lane >= 1  ? d1  : 0.0f) * u; }
    if (d2 != 0.0f) { u = __shfl_up(v, 2);  v += (lane >= 2  ? d2  : 0.0f) * u; }
    if (d4 != 0.0f) { u = __shfl_up(v, 4);  v += (lane >= 4  ? d4  : 0.0f) * u; }
    if (d8 != 0.0f) { u = __shfl_up(v, 8);  v += (lane >= 8  ? d8  : 0.0f) * u; }
    if (d16 != 0.0f) { u = __shfl_up(v, 16); v += (lane >= 16 ? d16 : 0.0f) * u; }
    if (d32 != 0.0f) { u = __shfl_up(v, 32); v += (lane >= 32 ? d32 : 0.0f) * u; }
    return v;
}

__device__ __forceinline__ float huber(float pd, float td) {
    float dir = pd * td;
    float se  = fabsf(pd - td);
    float mm  = fmaxf(1.0f - dir, 0.0f);
    float q   = 0.5f * mm * mm;
    return dir < 0.0f ? se : q;
}

__global__ void __launch_bounds__(256) msl_main(const float* __restrict__ pred,
                                                const float* __restrict__ targ,
                                                float* __restrict__ out) {
    const int lane = threadIdx.x & 63;
    const int wave = threadIdx.x >> 6;
    const int g    = blockIdx.x * WPB + wave;   // global wave id
    const int row  = g >> 3;                    // NSEG = 8
    const int seg  = g & 7;
    const bool s0  = (seg == 0);
    const bool lz  = (lane == 0);

    // seg 0 reads [0, EXT) with exact IC (pe[0]=x[0]); seg>0 reads WARM extra
    // elements before its output range and warms up from a zero initial state
    // ((1-a)^257 < 2e-12 => negligible). Loss is masked to [lo, hi).
    const int ext_base = s0 ? 0 : seg * SEG_OUT - WARM;
    const int lo = s0 ? 1 : WARM;        // skip t=0 globally; skip warmup
    const int hi = s0 ? SEG_OUT : EXT;

    const float* __restrict__ prow = pred + (size_t)row * S_LEN + ext_base + lane * PER_LANE;
    const float* __restrict__ trow = targ + (size_t)row * S_LEN + ext_base + lane * PER_LANE;

    float xp[PER_LANE], xt[PER_LANE];
    const float4* p4 = reinterpret_cast<const float4*>(prow);
    const float4* t4 = reinterpret_cast<const float4*>(trow);
#pragma unroll
    for (int j = 0; j < PER_LANE / 4; ++j) {
        float4 a = p4[j];
        float4 b = t4[j];
        xp[4 * j + 0] = a.x; xp[4 * j + 1] = a.y; xp[4 * j + 2] = a.z; xp[4 * j + 3] = a.w;
        xt[4 * j + 0] = b.x; xt[4 * j + 1] = b.y; xt[4 * j + 2] = b.z; xt[4 * j + 3] = b.w;
    }

    // ---- pass 1: lane-local EMA (zero carry-in; seg0/lane0 gets exact IC) ----
    const float ip = (lz && s0) ? xp[0] : 0.0f;
    const float it = (lz && s0) ? xt[0] : 0.0f;
    float Lp0 = ip, Lp1 = ip, Lp2 = ip;
    float Lt0 = it, Lt1 = it, Lt2 = it;
#pragma unroll
    for (int j = 0; j < PER_LANE; ++j) {
        Lp0 += A0f * (xp[j] - Lp0);
        Lp1 += A1f * (xp[j] - Lp1);
        Lp2 += A2f * (xp[j] - Lp2);
        Lt0 += A0f * (xt[j] - Lt0);
        Lt1 += A1f * (xt[j] - Lt1);
        Lt2 += A2f * (xt[j] - Lt2);
    }

    // ---- wave scan: exact (to fp32) EMA state at the end of each lane's chunk ----
    float vp0 = ema_scan(Lp0, lane, D0_1, D0_2, D0_4, D0_8, D0_16, D0_32);
    float vp1 = ema_scan(Lp1, lane, D1_1, D1_2, D1_4, D1_8, D1_16, D1_32);
    float vp2 = ema_scan(Lp2, lane, D2_1, D2_2, D2_4, D2_8, D2_16, D2_32);
    float vt0 = ema_scan(Lt0, lane, D0_1, D0_2, D0_4, D0_8, D0_16, D0_32);
    float vt1 = ema_scan(Lt1, lane, D1_1, D1_2, D1_4, D1_8, D1_16, D1_32);
    float vt2 = ema_scan(Lt2, lane, D2_1, D2_2, D2_4, D2_8, D2_16, D2_32);

    // exclusive carry = EMA state just before this lane's chunk
    float cp0 = __shfl_up(vp0, 1), cp1 = __shfl_up(vp1, 1), cp2 = __shfl_up(vp2, 1);
    float ct0 = __shfl_up(vt0, 1), ct1 = __shfl_up(vt1, 1), ct2 = __shfl_up(vt2, 1);

    float yp0 = lz ? ip : cp0;
    float yp1 = lz ? ip : cp1;
    float yp2 = lz ? ip : cp2;
    float yt0 = lz ? it : ct0;
    float yt1 = lz ? it : ct1;
    float yt2 = lz ? it : ct2;

    // ---- pass 2: replay with exact carry; pd_t = pe_t - pe_{t-1} = a*(x_t - pe_{t-1}) ----
    float acc0 = 0.f, acc1 = 0.f, acc2 = 0.f;
    const int ebase = lane * PER_LANE;
#pragma unroll
    for (int j = 0; j < PER_LANE; ++j) {
        float pd0 = A0f * (xp[j] - yp0); yp0 += pd0;
        float td0 = A0f * (xt[j] - yt0); yt0 += td0;
        float pd1 = A1f * (xp[j] - yp1); yp1 += pd1;
        float td1 = A1f * (xt[j] - yt1); yt1 += td1;
        float pd2 = A2f * (xp[j] - yp2); yp2 += pd2;
        float td2 = A2f * (xt[j] - yt2); yt2 += td2;

        const int e = ebase + j;
        const float m = (e >= lo && e < hi) ? 1.0f : 0.0f;
        acc0 += m * huber(pd0, td0);
        acc1 += m * huber(pd1, td1);
        acc2 += m * huber(pd2, td2);
    }

    // weight scales, reduce wave -> block -> global atomic
    float wacc = 0.5f * acc0 + 0.3f * acc1 + 0.2f * acc2;
#pragma unroll
    for (int o = 32; o > 0; o >>= 1) wacc += __shfl_down(wacc, o);

    __shared__ float sred[WPB];
    if (lz) sred[wave] = wacc;
    __syncthreads();
    if (threadIdx.x == 0) {
        const float scale = (float)(1.0 / ((double)(S_LEN - 1) * (double)B_ROWS));
        atomicAdd(out, (sred[0] + sred[1] + sred[2] + sred[3]) * scale);
    }
}

extern "C" void kernel_launch(void* const* d_in, const int* in_sizes, int n_in,
                              void* d_out, int out_size, void* d_ws, size_t ws_size,
                              hipStream_t stream) {
    const float* pred = (const float*)d_in[0];
    const float* targ = (const float*)d_in[1];
    float* out = (float*)d_out;

    hipMemsetAsync(out, 0, sizeof(float), stream);
    msl_main<<<NBLOCKS, 256, 0, stream>>>(pred, targ, out);
}

// Round 3
// 173.144 us; speedup vs baseline: 1.0059x; 1.0059x over previous
//
#include <hip/hip_runtime.h>

#define B_ROWS 2048
#define S_LEN 8192
#define SEG_OUT 1024
#define WARM 256
#define EXT (SEG_OUT + WARM)            // 1280 = 64 * 20
#define PER_LANE 20                     // floats per lane = 5 float4 (80 B, 16B-aligned)
#define NSEG (S_LEN / SEG_OUT)          // 8 segments per row
#define WPB 4                           // waves per block
#define NBLOCKS (B_ROWS * NSEG / WPB)   // 4096 blocks

// ---- compile-time decay constants, trimmed below 1e-12 ----
constexpr double cpowi(double b, int e) { double r = 1.0; for (int i = 0; i < e; ++i) r *= b; return r; }
constexpr float trim(double x) { return (x < 1e-12 && x > -1e-12) ? 0.0f : (float)x; }

#define A0f 0.1f
#define A1f 0.3f
#define A2f 0.6f

// d_k = (1-alpha)^(PER_LANE * 2^k)
constexpr float D0_1 = trim(cpowi(0.9, 20)),  D0_2 = trim(cpowi(0.9, 40)),  D0_4 = trim(cpowi(0.9, 80));
constexpr float D0_8 = trim(cpowi(0.9, 160)), D0_16 = trim(cpowi(0.9, 320)), D0_32 = trim(cpowi(0.9, 640));
constexpr float D1_1 = trim(cpowi(0.7, 20)),  D1_2 = trim(cpowi(0.7, 40)),  D1_4 = trim(cpowi(0.7, 80));
constexpr float D1_8 = trim(cpowi(0.7, 160)), D1_16 = trim(cpowi(0.7, 320)), D1_32 = trim(cpowi(0.7, 640));
constexpr float D2_1 = trim(cpowi(0.4, 20)),  D2_2 = trim(cpowi(0.4, 40)),  D2_4 = trim(cpowi(0.4, 80));
constexpr float D2_8 = trim(cpowi(0.4, 160)), D2_16 = trim(cpowi(0.4, 320)), D2_32 = trim(cpowi(0.4, 640));

__device__ __forceinline__ float ema_scan(float v, int lane,
                                          float d1, float d2, float d4,
                                          float d8, float d16, float d32) {
    float u;
    if (d1 != 0.0f) { u = __shfl_up(v, 1);  v += (lane >= 1  ? d1  : 0.0f) * u; }
    if (d2 != 0.0f) { u = __shfl_up(v, 2);  v += (lane >= 2  ? d2  : 0.0f) * u; }
    if (d4 != 0.0f) { u = __shfl_up(v, 4);  v += (lane >= 4  ? d4  : 0.0f) * u; }
    if (d8 != 0.0f) { u = __shfl_up(v, 8);  v += (lane >= 8  ? d8  : 0.0f) * u; }
    if (d16 != 0.0f) { u = __shfl_up(v, 16); v += (lane >= 16 ? d16 : 0.0f) * u; }
    if (d32 != 0.0f) { u = __shfl_up(v, 32); v += (lane >= 32 ? d32 : 0.0f) * u; }
    return v;
}

__device__ __forceinline__ float huber(float pd, float td) {
    float dir = pd * td;
    float se  = fabsf(pd - td);
    float mm  = fmaxf(1.0f - dir, 0.0f);
    float q   = 0.5f * mm * mm;
    return dir < 0.0f ? se : q;
}

// pass-1 EMA update for one element (both inputs, all 3 alphas)
#define PASS1(px, tx)                                         \
    Lp0 += A0f * ((px) - Lp0); Lp1 += A1f * ((px) - Lp1);     \
    Lp2 += A2f * ((px) - Lp2);                                \
    Lt0 += A0f * ((tx) - Lt0); Lt1 += A1f * ((tx) - Lt1);     \
    Lt2 += A2f * ((tx) - Lt2);

// pass-2: deltas + huber, masked to [lo,hi)
#define PASS2(px, tx, J) {                                    \
    float pd0 = A0f * ((px) - yp0); yp0 += pd0;               \
    float td0 = A0f * ((tx) - yt0); yt0 += td0;               \
    float pd1 = A1f * ((px) - yp1); yp1 += pd1;               \
    float td1 = A1f * ((tx) - yt1); yt1 += td1;               \
    float pd2 = A2f * ((px) - yp2); yp2 += pd2;               \
    float td2 = A2f * ((tx) - yt2); yt2 += td2;               \
    const int e_ = ebase + (J);                               \
    const float m_ = (e_ >= lo && e_ < hi) ? 1.0f : 0.0f;     \
    acc0 += m_ * huber(pd0, td0);                             \
    acc1 += m_ * huber(pd1, td1);                             \
    acc2 += m_ * huber(pd2, td2); }

__global__ void __launch_bounds__(256, 4) msl_main(const float* __restrict__ pred,
                                                   const float* __restrict__ targ,
                                                   float* __restrict__ out) {
    const int lane = threadIdx.x & 63;
    const int wave = threadIdx.x >> 6;
    const int g    = blockIdx.x * WPB + wave;   // global wave id
    const int row  = g >> 3;                    // NSEG = 8
    const int seg  = g & 7;
    const bool s0  = (seg == 0);
    const bool lz  = (lane == 0);

    // seg 0 reads [0, EXT) with exact IC (pe[0]=x[0]); seg>0 warms up from a
    // zero state over WARM=256 extra elements ((1-a)^257 < 2e-12 -> exact in fp32).
    const int ext_base = s0 ? 0 : seg * SEG_OUT - WARM;
    const int lo = s0 ? 1 : WARM;        // skip t=0 globally; skip warmup
    const int hi = s0 ? SEG_OUT : EXT;

    const float* __restrict__ prow = pred + (size_t)row * S_LEN + ext_base + lane * PER_LANE;
    const float* __restrict__ trow = targ + (size_t)row * S_LEN + ext_base + lane * PER_LANE;

    // named float4s -> guaranteed register residency (no indexable arrays)
    const float4* p4 = reinterpret_cast<const float4*>(prow);
    const float4* t4 = reinterpret_cast<const float4*>(trow);
    float4 p0 = p4[0], p1 = p4[1], p2 = p4[2], p3 = p4[3], p5 = p4[4];
    float4 t0 = t4[0], t1 = t4[1], t2 = t4[2], t3 = t4[3], t5 = t4[4];

    // ---- pass 1: lane-local EMA (zero carry-in; seg0/lane0 gets exact IC) ----
    const float ip = (lz && s0) ? p0.x : 0.0f;
    const float it = (lz && s0) ? t0.x : 0.0f;
    float Lp0 = ip, Lp1 = ip, Lp2 = ip;
    float Lt0 = it, Lt1 = it, Lt2 = it;

    PASS1(p0.x, t0.x) PASS1(p0.y, t0.y) PASS1(p0.z, t0.z) PASS1(p0.w, t0.w)
    PASS1(p1.x, t1.x) PASS1(p1.y, t1.y) PASS1(p1.z, t1.z) PASS1(p1.w, t1.w)
    PASS1(p2.x, t2.x) PASS1(p2.y, t2.y) PASS1(p2.z, t2.z) PASS1(p2.w, t2.w)
    PASS1(p3.x, t3.x) PASS1(p3.y, t3.y) PASS1(p3.z, t3.z) PASS1(p3.w, t3.w)
    PASS1(p5.x, t5.x) PASS1(p5.y, t5.y) PASS1(p5.z, t5.z) PASS1(p5.w, t5.w)

    // ---- wave scan: EMA state at the end of each lane's chunk ----
    float vp0 = ema_scan(Lp0, lane, D0_1, D0_2, D0_4, D0_8, D0_16, D0_32);
    float vp1 = ema_scan(Lp1, lane, D1_1, D1_2, D1_4, D1_8, D1_16, D1_32);
    float vp2 = ema_scan(Lp2, lane, D2_1, D2_2, D2_4, D2_8, D2_16, D2_32);
    float vt0 = ema_scan(Lt0, lane, D0_1, D0_2, D0_4, D0_8, D0_16, D0_32);
    float vt1 = ema_scan(Lt1, lane, D1_1, D1_2, D1_4, D1_8, D1_16, D1_32);
    float vt2 = ema_scan(Lt2, lane, D2_1, D2_2, D2_4, D2_8, D2_16, D2_32);

    // exclusive carry = EMA state just before this lane's chunk
    float cp0 = __shfl_up(vp0, 1), cp1 = __shfl_up(vp1, 1), cp2 = __shfl_up(vp2, 1);
    float ct0 = __shfl_up(vt0, 1), ct1 = __shfl_up(vt1, 1), ct2 = __shfl_up(vt2, 1);

    float yp0 = lz ? ip : cp0;
    float yp1 = lz ? ip : cp1;
    float yp2 = lz ? ip : cp2;
    float yt0 = lz ? it : ct0;
    float yt1 = lz ? it : ct1;
    float yt2 = lz ? it : ct2;

    // ---- pass 2: replay with exact carry; pd_t = a*(x_t - pe_{t-1}) ----
    float acc0 = 0.f, acc1 = 0.f, acc2 = 0.f;
    const int ebase = lane * PER_LANE;

    PASS2(p0.x, t0.x, 0)  PASS2(p0.y, t0.y, 1)  PASS2(p0.z, t0.z, 2)  PASS2(p0.w, t0.w, 3)
    PASS2(p1.x, t1.x, 4)  PASS2(p1.y, t1.y, 5)  PASS2(p1.z, t1.z, 6)  PASS2(p1.w, t1.w, 7)
    PASS2(p2.x, t2.x, 8)  PASS2(p2.y, t2.y, 9)  PASS2(p2.z, t2.z, 10) PASS2(p2.w, t2.w, 11)
    PASS2(p3.x, t3.x, 12) PASS2(p3.y, t3.y, 13) PASS2(p3.z, t3.z, 14) PASS2(p3.w, t3.w, 15)
    PASS2(p5.x, t5.x, 16) PASS2(p5.y, t5.y, 17) PASS2(p5.z, t5.z, 18) PASS2(p5.w, t5.w, 19)

    // weight scales, reduce wave -> block -> global atomic
    float wacc = 0.5f * acc0 + 0.3f * acc1 + 0.2f * acc2;
#pragma unroll
    for (int o = 32; o > 0; o >>= 1) wacc += __shfl_down(wacc, o);

    __shared__ float sred[WPB];
    if (lz) sred[wave] = wacc;
    __syncthreads();
    if (threadIdx.x == 0) {
        const float scale = (float)(1.0 / ((double)(S_LEN - 1) * (double)B_ROWS));
        atomicAdd(out, (sred[0] + sred[1] + sred[2] + sred[3]) * scale);
    }
}

extern "C" void kernel_launch(void* const* d_in, const int* in_sizes, int n_in,
                              void* d_out, int out_size, void* d_ws, size_t ws_size,
                              hipStream_t stream) {
    const float* pred = (const float*)d_in[0];
    const float* targ = (const float*)d_in[1];
    float* out = (float*)d_out;

    hipMemsetAsync(out, 0, sizeof(float), stream);
    msl_main<<<NBLOCKS, 256, 0, stream>>>(pred, targ, out);
}

// Round 4
// 169.638 us; speedup vs baseline: 1.0267x; 1.0207x over previous
//
#include <hip/hip_runtime.h>

#define B_ROWS 2048
#define S_LEN 8192
#define SEG_OUT 1024
#define WARM 256
#define EXT (SEG_OUT + WARM)            // 1280 = 64 * 20
#define PER_LANE 20                     // floats per lane = 5 float4
#define NSEG (S_LEN / SEG_OUT)          // 8 segments per row
#define WPB 4                           // waves per block
#define NBLOCKS (B_ROWS * NSEG / WPB)   // 4096 blocks

// ---- compile-time decay constants, trimmed below 1e-12 ----
constexpr double cpowi(double b, int e) { double r = 1.0; for (int i = 0; i < e; ++i) r *= b; return r; }
constexpr float trim(double x) { return (x < 1e-12 && x > -1e-12) ? 0.0f : (float)x; }

#define A0f 0.1f
#define A1f 0.3f
#define A2f 0.6f

// d_k = (1-alpha)^(PER_LANE * 2^k)
constexpr float D0_1 = trim(cpowi(0.9, 20)),  D0_2 = trim(cpowi(0.9, 40)),  D0_4 = trim(cpowi(0.9, 80));
constexpr float D0_8 = trim(cpowi(0.9, 160)), D0_16 = trim(cpowi(0.9, 320)), D0_32 = trim(cpowi(0.9, 640));
constexpr float D1_1 = trim(cpowi(0.7, 20)),  D1_2 = trim(cpowi(0.7, 40)),  D1_4 = trim(cpowi(0.7, 80));
constexpr float D1_8 = trim(cpowi(0.7, 160)), D1_16 = trim(cpowi(0.7, 320)), D1_32 = trim(cpowi(0.7, 640));
constexpr float D2_1 = trim(cpowi(0.4, 20)),  D2_2 = trim(cpowi(0.4, 40)),  D2_4 = trim(cpowi(0.4, 80));
constexpr float D2_8 = trim(cpowi(0.4, 160)), D2_16 = trim(cpowi(0.4, 320)), D2_32 = trim(cpowi(0.4, 640));

__device__ __forceinline__ float ema_scan(float v, int lane,
                                          float d1, float d2, float d4,
                                          float d8, float d16, float d32) {
    float u;
    if (d1 != 0.0f) { u = __shfl_up(v, 1);  v += (lane >= 1  ? d1  : 0.0f) * u; }
    if (d2 != 0.0f) { u = __shfl_up(v, 2);  v += (lane >= 2  ? d2  : 0.0f) * u; }
    if (d4 != 0.0f) { u = __shfl_up(v, 4);  v += (lane >= 4  ? d4  : 0.0f) * u; }
    if (d8 != 0.0f) { u = __shfl_up(v, 8);  v += (lane >= 8  ? d8  : 0.0f) * u; }
    if (d16 != 0.0f) { u = __shfl_up(v, 16); v += (lane >= 16 ? d16 : 0.0f) * u; }
    if (d32 != 0.0f) { u = __shfl_up(v, 32); v += (lane >= 32 ? d32 : 0.0f) * u; }
    return v;
}

__device__ __forceinline__ float huber(float pd, float td) {
    float dir = pd * td;
    float se  = fabsf(pd - td);
    float mm  = fmaxf(1.0f - dir, 0.0f);
    float q   = 0.5f * mm * mm;
    return dir < 0.0f ? se : q;
}

#define PASS1(px, tx)                                         \
    Lp0 += A0f * ((px) - Lp0); Lp1 += A1f * ((px) - Lp1);     \
    Lp2 += A2f * ((px) - Lp2);                                \
    Lt0 += A0f * ((tx) - Lt0); Lt1 += A1f * ((tx) - Lt1);     \
    Lt2 += A2f * ((tx) - Lt2);

#define PASS2(px, tx, J) {                                    \
    float pd0 = A0f * ((px) - yp0); yp0 += pd0;               \
    float td0 = A0f * ((tx) - yt0); yt0 += td0;               \
    float pd1 = A1f * ((px) - yp1); yp1 += pd1;               \
    float td1 = A1f * ((tx) - yt1); yt1 += td1;               \
    float pd2 = A2f * ((px) - yp2); yp2 += pd2;               \
    float td2 = A2f * ((tx) - yt2); yt2 += td2;               \
    const int e_ = ebase + (J);                               \
    const float m_ = (e_ >= lo && e_ < hi) ? 1.0f : 0.0f;     \
    acc0 += m_ * huber(pd0, td0);                             \
    acc1 += m_ * huber(pd1, td1);                             \
    acc2 += m_ * huber(pd2, td2); }

__global__ void __launch_bounds__(256) msl_main(const float* __restrict__ pred,
                                                const float* __restrict__ targ,
                                                float* __restrict__ out) {
    const int lane = threadIdx.x & 63;
    const int wave = threadIdx.x >> 6;
    const int g    = blockIdx.x * WPB + wave;   // global wave id
    const int row  = g >> 3;                    // NSEG = 8
    const int seg  = g & 7;
    const bool s0  = (seg == 0);
    const bool lz  = (lane == 0);

    // seg 0 reads [0, EXT) with exact IC (pe[0]=x[0]); seg>0 warms up from a
    // zero state over WARM=256 extra elements ((1-a)^257 < 2e-12 -> exact in fp32).
    const int ext_base = s0 ? 0 : seg * SEG_OUT - WARM;
    const int lo = s0 ? 1 : WARM;        // skip t=0 globally; skip warmup
    const int hi = s0 ? SEG_OUT : EXT;

    const float* __restrict__ prow = pred + (size_t)row * S_LEN + ext_base + lane * PER_LANE;
    const float* __restrict__ trow = targ + (size_t)row * S_LEN + ext_base + lane * PER_LANE;

    const float4* p4 = reinterpret_cast<const float4*>(prow);
    const float4* t4 = reinterpret_cast<const float4*>(trow);
    float4 P0 = p4[0], P1 = p4[1], P2 = p4[2], P3 = p4[3], P4 = p4[4];
    float4 T0 = t4[0], T1 = t4[1], T2 = t4[2], T3 = t4[3], T4 = t4[4];

    // unpack to 40 named scalars so we can pin them in VGPRs
    float pa0 = P0.x, pa1 = P0.y, pa2 = P0.z, pa3 = P0.w;
    float pa4 = P1.x, pa5 = P1.y, pa6 = P1.z, pa7 = P1.w;
    float pa8 = P2.x, pa9 = P2.y, pa10 = P2.z, pa11 = P2.w;
    float pa12 = P3.x, pa13 = P3.y, pa14 = P3.z, pa15 = P3.w;
    float pa16 = P4.x, pa17 = P4.y, pa18 = P4.z, pa19 = P4.w;
    float ta0 = T0.x, ta1 = T0.y, ta2 = T0.z, ta3 = T0.w;
    float ta4 = T1.x, ta5 = T1.y, ta6 = T1.z, ta7 = T1.w;
    float ta8 = T2.x, ta9 = T2.y, ta10 = T2.z, ta11 = T2.w;
    float ta12 = T3.x, ta13 = T3.y, ta14 = T3.z, ta15 = T3.w;
    float ta16 = T4.x, ta17 = T4.y, ta18 = T4.z, ta19 = T4.w;

    // ---- pass 1: lane-local EMA (zero carry-in; seg0/lane0 gets exact IC) ----
    const float ip = (lz && s0) ? pa0 : 0.0f;
    const float it = (lz && s0) ? ta0 : 0.0f;
    float Lp0 = ip, Lp1 = ip, Lp2 = ip;
    float Lt0 = it, Lt1 = it, Lt2 = it;

    PASS1(pa0, ta0)   PASS1(pa1, ta1)   PASS1(pa2, ta2)   PASS1(pa3, ta3)
    PASS1(pa4, ta4)   PASS1(pa5, ta5)   PASS1(pa6, ta6)   PASS1(pa7, ta7)
    PASS1(pa8, ta8)   PASS1(pa9, ta9)   PASS1(pa10, ta10) PASS1(pa11, ta11)
    PASS1(pa12, ta12) PASS1(pa13, ta13) PASS1(pa14, ta14) PASS1(pa15, ta15)
    PASS1(pa16, ta16) PASS1(pa17, ta17) PASS1(pa18, ta18) PASS1(pa19, ta19)

    // ---- wave scan: EMA state at the end of each lane's chunk ----
    float vp0 = ema_scan(Lp0, lane, D0_1, D0_2, D0_4, D0_8, D0_16, D0_32);
    float vp1 = ema_scan(Lp1, lane, D1_1, D1_2, D1_4, D1_8, D1_16, D1_32);
    float vp2 = ema_scan(Lp2, lane, D2_1, D2_2, D2_4, D2_8, D2_16, D2_32);
    float vt0 = ema_scan(Lt0, lane, D0_1, D0_2, D0_4, D0_8, D0_16, D0_32);
    float vt1 = ema_scan(Lt1, lane, D1_1, D1_2, D1_4, D1_8, D1_16, D1_32);
    float vt2 = ema_scan(Lt2, lane, D2_1, D2_2, D2_4, D2_8, D2_16, D2_32);

    // exclusive carry = EMA state just before this lane's chunk
    float cp0 = __shfl_up(vp0, 1), cp1 = __shfl_up(vp1, 1), cp2 = __shfl_up(vp2, 1);
    float ct0 = __shfl_up(vt0, 1), ct1 = __shfl_up(vt1, 1), ct2 = __shfl_up(vt2, 1);

    float yp0 = lz ? ip : cp0;
    float yp1 = lz ? ip : cp1;
    float yp2 = lz ? ip : cp2;
    float yt0 = lz ? it : ct0;
    float yt1 = lz ? it : ct1;
    float yt2 = lz ? it : ct2;

    // Pin the 40 x-values in VGPRs across the scan: pass 2 MUST consume these
    // registers (compiler cannot rematerialize them as global re-loads).
    asm volatile("" : "+v"(pa0), "+v"(pa1), "+v"(pa2), "+v"(pa3), "+v"(pa4),
                      "+v"(pa5), "+v"(pa6), "+v"(pa7), "+v"(pa8), "+v"(pa9),
                      "+v"(pa10), "+v"(pa11), "+v"(pa12), "+v"(pa13), "+v"(pa14),
                      "+v"(pa15), "+v"(pa16), "+v"(pa17), "+v"(pa18), "+v"(pa19));
    asm volatile("" : "+v"(ta0), "+v"(ta1), "+v"(ta2), "+v"(ta3), "+v"(ta4),
                      "+v"(ta5), "+v"(ta6), "+v"(ta7), "+v"(ta8), "+v"(ta9),
                      "+v"(ta10), "+v"(ta11), "+v"(ta12), "+v"(ta13), "+v"(ta14),
                      "+v"(ta15), "+v"(ta16), "+v"(ta17), "+v"(ta18), "+v"(ta19));

    // ---- pass 2: replay with exact carry; pd_t = a*(x_t - pe_{t-1}) ----
    float acc0 = 0.f, acc1 = 0.f, acc2 = 0.f;
    const int ebase = lane * PER_LANE;

    PASS2(pa0, ta0, 0)    PASS2(pa1, ta1, 1)    PASS2(pa2, ta2, 2)    PASS2(pa3, ta3, 3)
    PASS2(pa4, ta4, 4)    PASS2(pa5, ta5, 5)    PASS2(pa6, ta6, 6)    PASS2(pa7, ta7, 7)
    PASS2(pa8, ta8, 8)    PASS2(pa9, ta9, 9)    PASS2(pa10, ta10, 10) PASS2(pa11, ta11, 11)
    PASS2(pa12, ta12, 12) PASS2(pa13, ta13, 13) PASS2(pa14, ta14, 14) PASS2(pa15, ta15, 15)
    PASS2(pa16, ta16, 16) PASS2(pa17, ta17, 17) PASS2(pa18, ta18, 18) PASS2(pa19, ta19, 19)

    // weight scales, reduce wave -> block -> global atomic
    float wacc = 0.5f * acc0 + 0.3f * acc1 + 0.2f * acc2;
#pragma unroll
    for (int o = 32; o > 0; o >>= 1) wacc += __shfl_down(wacc, o);

    __shared__ float sred[WPB];
    if (lz) sred[wave] = wacc;
    __syncthreads();
    if (threadIdx.x == 0) {
        const float scale = (float)(1.0 / ((double)(S_LEN - 1) * (double)B_ROWS));
        atomicAdd(out, (sred[0] + sred[1] + sred[2] + sred[3]) * scale);
    }
}

extern "C" void kernel_launch(void* const* d_in, const int* in_sizes, int n_in,
                              void* d_out, int out_size, void* d_ws, size_t ws_size,
                              hipStream_t stream) {
    const float* pred = (const float*)d_in[0];
    const float* targ = (const float*)d_in[1];
    float* out = (float*)d_out;

    hipMemsetAsync(out, 0, sizeof(float), stream);
    msl_main<<<NBLOCKS, 256, 0, stream>>>(pred, targ, out);
}